// Round 1
// 497.557 us; speedup vs baseline: 1.0052x; 1.0052x over previous
//
#include <hip/hip_runtime.h>
#include <cstdint>
#include <cstddef>

// Problem constants (fixed by reference: x (4,2048,4096) f32, weight (4096,4096) f32)
#define MDIM 8192
#define NDIM 4096
#define KDIM 4096
#define TERN_THRESH 0.1f

typedef unsigned short u16;
typedef __bf16 bf16x8 __attribute__((ext_vector_type(8)));
typedef float f32x4 __attribute__((ext_vector_type(4)));
typedef u16 u16x8 __attribute__((ext_vector_type(8)));

// ---------------------------------------------------------------- helpers ---

__device__ __forceinline__ u16 f2bf(float f) {
  // round-to-nearest-even f32 -> bf16 (inputs are finite, no NaN handling)
  unsigned u = __float_as_uint(f);
  u += 0x7FFFu + ((u >> 16) & 1u);
  return (u16)(u >> 16);
}

__device__ __forceinline__ u16 tern_bf16(float w) {
  // sign(w) * (|w| > 0.1)  as bf16 bits: +1=0x3F80, -1=0xBF80, 0=0
  return w > TERN_THRESH ? (u16)0x3F80u : (w < -TERN_THRESH ? (u16)0xBF80u : (u16)0u);
}

// async global -> LDS, 16 B per lane; LDS side is wave-uniform base + lane*16
__device__ __forceinline__ void load_lds16(const u16* g, u16* s) {
  __builtin_amdgcn_global_load_lds(
      (__attribute__((address_space(1))) void*)(void*)(g),
      (__attribute__((address_space(3))) void*)(void*)(s),
      16, 0, 0);
}

// ------------------------------------------------------- conversion kernel ---
// UNCHANGED this round (verified path). Fused: blocks [0, XBLOCKS) convert x
// f32->bf16; the rest ternarize weight. 8 elements per thread.

#define XBLOCKS ((MDIM * (size_t)KDIM) / (8 * 256))   // 16384
#define WBLOCKS ((NDIM * (size_t)KDIM) / (8 * 256))   //  8192

__global__ __launch_bounds__(256) void cvt_kernel(const float* __restrict__ x,
                                                  u16* __restrict__ xb,
                                                  const float* __restrict__ w,
                                                  u16* __restrict__ qb) {
  size_t b = blockIdx.x;
  if (b < XBLOCKS) {
    size_t i = b * 256 + threadIdx.x;
    const f32x4* x4 = (const f32x4*)x;
    f32x4 a = __builtin_nontemporal_load(&x4[2 * i]);
    f32x4 c = __builtin_nontemporal_load(&x4[2 * i + 1]);
    u16x8 o;
    o[0] = f2bf(a[0]); o[1] = f2bf(a[1]); o[2] = f2bf(a[2]); o[3] = f2bf(a[3]);
    o[4] = f2bf(c[0]); o[5] = f2bf(c[1]); o[6] = f2bf(c[2]); o[7] = f2bf(c[3]);
    ((u16x8*)xb)[i] = o;
  } else {
    size_t i = (b - XBLOCKS) * 256 + threadIdx.x;
    const f32x4* w4 = (const f32x4*)w;
    f32x4 a = __builtin_nontemporal_load(&w4[2 * i]);
    f32x4 c = __builtin_nontemporal_load(&w4[2 * i + 1]);
    u16x8 o;
    o[0] = tern_bf16(a[0]); o[1] = tern_bf16(a[1]); o[2] = tern_bf16(a[2]); o[3] = tern_bf16(a[3]);
    o[4] = tern_bf16(c[0]); o[5] = tern_bf16(c[1]); o[6] = tern_bf16(c[2]); o[7] = tern_bf16(c[3]);
    ((u16x8*)qb)[i] = o;
  }
}

// ---------------------------------------------------------------- GEMM ------
// R3: 256x256 tile, BK=64, 512 threads = 8 waves (2 M x 4 N), per-wave output
// 128x64 (8x4 grid of 16x16x32 MFMA frags). 4-phase-per-K-tile counted-vmcnt
// pipeline (T3+T4 of the 8-phase template), double-buffered 128 KiB LDS.
//
// Stage units per K-tile (16 KB each, 2 global_load_lds dwordx4 / thread):
//   U0 = A k-lo (256 rows x k[0,32)), U1 = B k-lo, U2 = A k-hi, U3 = B k-hi
// Phase p of tile t issues stage unit Up of tile t+1 into buf[t+1 & 1].
//   phase 0: ds_read A-lo Mrep0-3 + B-lo    -> 16 MFMA (acc[0..3][*], klo)
//   phase 1: ds_read A-lo Mrep4-7           -> 16 MFMA (acc[4..7][*], klo)  vmcnt(4)
//   phase 2: ds_read A-hi Mrep0-3 + B-hi    -> 16 MFMA (acc[0..3][*], khi)
//   phase 3: ds_read A-hi Mrep4-7           -> 16 MFMA (acc[4..7][*], khi)  vmcnt(4)
// vmcnt(4) leaves 2 units (4 loads) in flight -> never drains to 0 in-loop.
// Wait at end of phase 3 guarantees U0,U1(t+1) before next tile's phase-0
// reads; wait at end of phase 1 guarantees U2,U3(t) before phase-2 reads.
// Raw s_barrier (NOT __syncthreads -> would emit vmcnt(0)); asm("" ::: mem)
// after each barrier pins reads/stages below it (cross-wave visibility is
// vmcnt-before-barrier collective).
//
// LDS layout per unit (256 rows x 4 chunks of 16 B): linear chunk c holds
// global (row = c>>2, kchunk = (c&3) ^ ((row>>1)&3)). Pre-swizzled GLOBAL
// source + linear LDS dest (global_load_lds rule), same XOR on the read side.
// Frag read byte addr mod 128 = (row&1)*64 + ((quad^((row>>1)&3))*16): a
// quad's 16 lanes hit all 8 16-B slots twice = 2-way = conflict-free.

#define NT (KDIM / 64)

#define BARRIER() __builtin_amdgcn_s_barrier()
#define FENCE()   asm volatile("" ::: "memory")
#define VMCNT4()  asm volatile("s_waitcnt vmcnt(4)" ::: "memory")

#define MFMA_BLK(I0)                                                         \
  do {                                                                       \
    _Pragma("unroll") for (int _i = 0; _i < 4; ++_i) {                       \
      _Pragma("unroll") for (int _j = 0; _j < 4; ++_j) {                     \
        acc[(I0) + _i][_j] = __builtin_amdgcn_mfma_f32_16x16x32_bf16(        \
            af[_i], bf[_j], acc[(I0) + _i][_j], 0, 0, 0);                    \
      }                                                                      \
    }                                                                        \
  } while (0)

__global__ __launch_bounds__(512, 2) void gemm_tern_kernel(
    const u16* __restrict__ Xb,     // [MDIM][KDIM] bf16 bits
    const u16* __restrict__ Qb,     // [NDIM][KDIM] bf16 bits
    const float* __restrict__ bias, // [NDIM]
    float* __restrict__ C) {        // [MDIM][NDIM]
  // per operand: [2 dbuf][2 k-half][256 rows][4 chunks][8 u16] = 64 KiB
  __shared__ __attribute__((aligned(16))) u16 As[4 * 8192];
  __shared__ __attribute__((aligned(16))) u16 Bs[4 * 8192];

  const int tid  = threadIdx.x;
  const int lane = tid & 63;
  const int wv   = tid >> 6;
  const int wm   = wv >> 2;       // 0..1  (M wave row)
  const int wn   = wv & 3;        // 0..3  (N wave col)
  const int quad = lane >> 4;     // 0..3
  const int l16  = lane & 15;

  // XCD-aware bijective swizzle: 512 wgs, 8 XCDs, 64 contiguous per XCD.
  // Each XCD owns a 4-row x 16-col band of output tiles (A panels L2-reused).
  const int orig    = blockIdx.y * 16 + blockIdx.x;
  const int wg      = (orig & 7) * 64 + (orig >> 3);
  const int rowBase = (wg >> 4) * 256;   // M
  const int colBase = (wg & 15) * 256;   // N

  // Staging: thread covers unit-chunks c = tid and tid+512.
  // Global source pre-swizzled: row = c>>2, kchunk = (c&3) ^ ((row>>1)&3).
  const u16* gA[2];
  const u16* gB[2];
  int sOff[2];
#pragma unroll
  for (int j = 0; j < 2; ++j) {
    int c  = j * 512 + tid;
    int r  = c >> 2;
    int qg = (c & 3) ^ ((r >> 1) & 3);
    gA[j]   = Xb + (size_t)(rowBase + r) * KDIM + qg * 8;
    gB[j]   = Qb + (size_t)(colBase + r) * KDIM + qg * 8;
    sOff[j] = c * 8;  // u16 elements within the 8192-elem unit region
  }

#define STAGE_A(b, h, ko)                                                        \
  do {                                                                           \
    load_lds16(gA[0] + (ko) + (h) * 32, (u16*)As + ((b) * 2 + (h)) * 8192 + sOff[0]); \
    load_lds16(gA[1] + (ko) + (h) * 32, (u16*)As + ((b) * 2 + (h)) * 8192 + sOff[1]); \
  } while (0)
#define STAGE_B(b, h, ko)                                                        \
  do {                                                                           \
    load_lds16(gB[0] + (ko) + (h) * 32, (u16*)Bs + ((b) * 2 + (h)) * 8192 + sOff[0]); \
    load_lds16(gB[1] + (ko) + (h) * 32, (u16*)Bs + ((b) * 2 + (h)) * 8192 + sOff[1]); \
  } while (0)

  // Fragment LDS element offsets (within a unit region), swizzle-matched.
  int ac[8], bc[4];
#pragma unroll
  for (int i = 0; i < 8; ++i) {
    int r = wm * 128 + i * 16 + l16;
    ac[i] = (r * 4 + (quad ^ ((r >> 1) & 3))) * 8;
  }
#pragma unroll
  for (int j = 0; j < 4; ++j) {
    int r = wn * 64 + j * 16 + l16;
    bc[j] = (r * 4 + (quad ^ ((r >> 1) & 3))) * 8;
  }

#define RD_A(d, i, b, kk) d = *(const bf16x8*)((const u16*)As + ((b) * 2 + (kk)) * 8192 + ac[i])
#define RD_B(d, j, b, kk) d = *(const bf16x8*)((const u16*)Bs + ((b) * 2 + (kk)) * 8192 + bc[j])

  f32x4 acc[8][4] = {};
  bf16x8 af[4], bf[4];

  // Prologue: stage tile 0 into buf 0, issue order U0,U1,U2,U3.
  STAGE_A(0, 0, 0);
  STAGE_B(0, 0, 0);
  STAGE_A(0, 1, 0);
  STAGE_B(0, 1, 0);
  VMCNT4();          // U0,U1 of tile 0 complete (2 units stay in flight)
  BARRIER();
  FENCE();

  int cur = 0;
  for (int t = 0; t < NT; ++t) {
    const int nxt = cur ^ 1;
    const int kn  = (t + 1 < NT) ? (t + 1) * 64 : 0;  // last-tile stage wraps (unused, keeps vmcnt math uniform)

    // ---- phase 0: k-lo, Mreps 0-3 (+ all B-lo) ----
    RD_A(af[0], 0, cur, 0); RD_A(af[1], 1, cur, 0);
    RD_A(af[2], 2, cur, 0); RD_A(af[3], 3, cur, 0);
    RD_B(bf[0], 0, cur, 0); RD_B(bf[1], 1, cur, 0);
    RD_B(bf[2], 2, cur, 0); RD_B(bf[3], 3, cur, 0);
    STAGE_A(nxt, 0, kn);
    BARRIER(); FENCE();
    __builtin_amdgcn_s_setprio(1);
    MFMA_BLK(0);
    __builtin_amdgcn_s_setprio(0);
    BARRIER(); FENCE();

    // ---- phase 1: k-lo, Mreps 4-7 ----
    RD_A(af[0], 4, cur, 0); RD_A(af[1], 5, cur, 0);
    RD_A(af[2], 6, cur, 0); RD_A(af[3], 7, cur, 0);
    STAGE_B(nxt, 0, kn);
    BARRIER(); FENCE();
    __builtin_amdgcn_s_setprio(1);
    MFMA_BLK(4);
    __builtin_amdgcn_s_setprio(0);
    VMCNT4();        // drains U2(t),U3(t) -> phase 2/3 reads safe after barrier
    BARRIER(); FENCE();

    // ---- phase 2: k-hi, Mreps 0-3 (+ all B-hi) ----
    RD_A(af[0], 0, cur, 1); RD_A(af[1], 1, cur, 1);
    RD_A(af[2], 2, cur, 1); RD_A(af[3], 3, cur, 1);
    RD_B(bf[0], 0, cur, 1); RD_B(bf[1], 1, cur, 1);
    RD_B(bf[2], 2, cur, 1); RD_B(bf[3], 3, cur, 1);
    STAGE_A(nxt, 1, kn);
    BARRIER(); FENCE();
    __builtin_amdgcn_s_setprio(1);
    MFMA_BLK(0);
    __builtin_amdgcn_s_setprio(0);
    BARRIER(); FENCE();

    // ---- phase 3: k-hi, Mreps 4-7 ----
    RD_A(af[0], 4, cur, 1); RD_A(af[1], 5, cur, 1);
    RD_A(af[2], 6, cur, 1); RD_A(af[3], 7, cur, 1);
    STAGE_B(nxt, 1, kn);
    BARRIER(); FENCE();
    __builtin_amdgcn_s_setprio(1);
    MFMA_BLK(4);
    __builtin_amdgcn_s_setprio(0);
    VMCNT4();        // drains U0(t+1),U1(t+1) -> next tile phase-0 reads safe
    BARRIER(); FENCE();

    cur = nxt;
  }

  // Epilogue: C/D layout col = lane&15, row = quad*4 + reg (same as verified R2)
  float bv[4];
#pragma unroll
  for (int j = 0; j < 4; ++j) bv[j] = bias[colBase + wn * 64 + j * 16 + l16];

#pragma unroll
  for (int i = 0; i < 8; ++i) {
#pragma unroll
    for (int r = 0; r < 4; ++r) {
      int grow = rowBase + wm * 128 + i * 16 + quad * 4 + r;
      float* crow = C + (size_t)grow * NDIM + colBase + wn * 64 + l16;
#pragma unroll
      for (int j = 0; j < 4; ++j) {
        crow[j * 16] = acc[i][j][r] + bv[j];
      }
    }
  }
}

// ---------------------------------------------------------------- launch ----

extern "C" void kernel_launch(void* const* d_in, const int* in_sizes, int n_in,
                              void* d_out, int out_size, void* d_ws, size_t ws_size,
                              hipStream_t stream) {
  const float* x    = (const float*)d_in[0];
  const float* w    = (const float*)d_in[1];
  const float* bias = (const float*)d_in[2];
  float* out = (float*)d_out;

  // workspace: Xb bf16 [MDIM*KDIM] then Qb bf16 [NDIM*KDIM]  (= 100.7 MB)
  u16* xb = (u16*)d_ws;
  u16* qb = xb + (size_t)MDIM * KDIM;

  cvt_kernel<<<(unsigned)(XBLOCKS + WBLOCKS), 256, 0, stream>>>(x, xb, w, qb);

  dim3 grid(NDIM / 256, MDIM / 256);   // (16, 32)
  gemm_tern_kernel<<<grid, 512, 0, stream>>>(xb, qb, bias, out);
}

// Round 2
// 456.981 us; speedup vs baseline: 1.0945x; 1.0888x over previous
//
#include <hip/hip_runtime.h>
#include <cstdint>
#include <cstddef>

// Problem constants (fixed by reference: x (4,2048,4096) f32, weight (4096,4096) f32)
#define MDIM 8192
#define NDIM 4096
#define KDIM 4096
#define TERN_THRESH 0.1f

typedef unsigned short u16;
typedef __bf16 bf16x8 __attribute__((ext_vector_type(8)));
typedef float f32x4 __attribute__((ext_vector_type(4)));
typedef u16 u16x8 __attribute__((ext_vector_type(8)));

// ---------------------------------------------------------------- helpers ---

__device__ __forceinline__ u16 f2bf(float f) {
  // round-to-nearest-even f32 -> bf16 (inputs are finite, no NaN handling)
  unsigned u = __float_as_uint(f);
  u += 0x7FFFu + ((u >> 16) & 1u);
  return (u16)(u >> 16);
}

__device__ __forceinline__ u16 tern_bf16(float w) {
  // sign(w) * (|w| > 0.1)  as bf16 bits: +1=0x3F80, -1=0xBF80, 0=0
  return w > TERN_THRESH ? (u16)0x3F80u : (w < -TERN_THRESH ? (u16)0xBF80u : (u16)0u);
}

// async global -> LDS, 16 B per lane; LDS side is wave-uniform base + lane*16
__device__ __forceinline__ void load_lds16(const u16* g, u16* s) {
  __builtin_amdgcn_global_load_lds(
      (__attribute__((address_space(1))) void*)(void*)(g),
      (__attribute__((address_space(3))) void*)(void*)(s),
      16, 0, 0);
}

// ------------------------------------------------------- conversion kernel ---
// UNCHANGED (verified path). Fused: blocks [0, XBLOCKS) convert x f32->bf16;
// the rest ternarize weight. 8 elements per thread.

#define XBLOCKS ((MDIM * (size_t)KDIM) / (8 * 256))   // 16384
#define WBLOCKS ((NDIM * (size_t)KDIM) / (8 * 256))   //  8192

__global__ __launch_bounds__(256) void cvt_kernel(const float* __restrict__ x,
                                                  u16* __restrict__ xb,
                                                  const float* __restrict__ w,
                                                  u16* __restrict__ qb) {
  size_t b = blockIdx.x;
  if (b < XBLOCKS) {
    size_t i = b * 256 + threadIdx.x;
    const f32x4* x4 = (const f32x4*)x;
    f32x4 a = __builtin_nontemporal_load(&x4[2 * i]);
    f32x4 c = __builtin_nontemporal_load(&x4[2 * i + 1]);
    u16x8 o;
    o[0] = f2bf(a[0]); o[1] = f2bf(a[1]); o[2] = f2bf(a[2]); o[3] = f2bf(a[3]);
    o[4] = f2bf(c[0]); o[5] = f2bf(c[1]); o[6] = f2bf(c[2]); o[7] = f2bf(c[3]);
    ((u16x8*)xb)[i] = o;
  } else {
    size_t i = (b - XBLOCKS) * 256 + threadIdx.x;
    const f32x4* w4 = (const f32x4*)w;
    f32x4 a = __builtin_nontemporal_load(&w4[2 * i]);
    f32x4 c = __builtin_nontemporal_load(&w4[2 * i + 1]);
    u16x8 o;
    o[0] = tern_bf16(a[0]); o[1] = tern_bf16(a[1]); o[2] = tern_bf16(a[2]); o[3] = tern_bf16(a[3]);
    o[4] = tern_bf16(c[0]); o[5] = tern_bf16(c[1]); o[6] = tern_bf16(c[2]); o[7] = tern_bf16(c[3]);
    ((u16x8*)qb)[i] = o;
  }
}

// ---------------------------------------------------------------- GEMM ------
// R2: 256x256 tile, BK=32, 512 threads = 8 waves (2M x 4N), per-wave output
// 128x64 (8 Mreps x 4 Nreps of 16x16x32 frags). 4-slot LDS ring, 3-tile
// prefetch lead, ONE counted vmcnt(8) per K-tile (T3+T4 shape).
//
// Per K-tile: 2 phases x 16 MFMA. Per phase: {ds_read frags, issue 2
// global_load_lds (half of tile t+3), barrier, setprio(1), 16 MFMA,
// setprio(0), [vmcnt(8) in ph1], barrier}.
//
// vmcnt ledger (steady state, end of ph1 of tile t): outstanding =
//   A,B(t+1) [issued in tile t-2] + A,B(t+2) [t-1] + A,B(t+3) [t] = 12 calls.
// vmcnt(8) drains the 4 oldest = A,B(t+1) -> tile t+1's reads safe after the
// barrier. In-flight never drops below 8 calls (2 tiles). Prologue stages
// tiles 0,1,2 (12 calls) then vmcnt(8) drains tile 0 -> uniform.
// Issue->wait distance = 5-6 phases (>=2500 cyc) >> L3/HBM latency.
// WAR: tile t+3 writes slot (t+3)&3 = tile t-1's slot; t-1's ds_reads
// completed before its final barrier (lgkm-waited by its own MFMA) -> safe.
// Tail: t+3 >= NTILE re-stages k=0 into dead slots (never read) to keep the
// vmcnt ledger uniform.
//
// LDS slot layout (per operand, 16 KB): [256 rows][4 chunks of 16B], linear
// chunk c holds global (row = c>>2, kchunk = (c&3) ^ ((row>>1)&3)). Global
// source pre-swizzled, LDS dest linear (global_load_lds rule), same XOR on
// read: frag addr/16 mod 8 = (4r + (quad ^ ((r>>1)&3))) mod 8 -> a quad's 16
// lanes hit all 8 slots exactly 2x = 2-way = conflict-free (R1: 0 conflicts).

#define NTILE (KDIM / 32)   // 128

#define BARRIER() __builtin_amdgcn_s_barrier()
#define FENCE()   asm volatile("" ::: "memory")
#define VMCNT8()  asm volatile("s_waitcnt vmcnt(8)" ::: "memory")

#define MFMA_BLK(I0)                                                         \
  do {                                                                       \
    _Pragma("unroll") for (int _i = 0; _i < 4; ++_i) {                       \
      _Pragma("unroll") for (int _j = 0; _j < 4; ++_j) {                     \
        acc[(I0) + _i][_j] = __builtin_amdgcn_mfma_f32_16x16x32_bf16(        \
            af[_i], bf[_j], acc[(I0) + _i][_j], 0, 0, 0);                    \
      }                                                                      \
    }                                                                        \
  } while (0)

__global__ __launch_bounds__(512, 2) void gemm_tern_kernel(
    const u16* __restrict__ Xb,     // [MDIM][KDIM] bf16 bits
    const u16* __restrict__ Qb,     // [NDIM][KDIM] bf16 bits
    const float* __restrict__ bias, // [NDIM]
    float* __restrict__ C) {        // [MDIM][NDIM]
  // 4 slots x (A 8192 + B 8192 u16) = 128 KiB
  __shared__ __attribute__((aligned(16))) u16 As[4 * 8192];
  __shared__ __attribute__((aligned(16))) u16 Bs[4 * 8192];

  const int tid  = threadIdx.x;
  const int lane = tid & 63;
  const int wv   = tid >> 6;
  const int wm   = wv >> 2;       // 0..1  (M wave row)
  const int wn   = wv & 3;        // 0..3  (N wave col)
  const int quad = lane >> 4;     // 0..3
  const int l16  = lane & 15;

  // XCD-aware bijective swizzle: 512 wgs, 8 XCDs, 64 contiguous per XCD.
  const int orig    = blockIdx.y * 16 + blockIdx.x;
  const int wg      = (orig & 7) * 64 + (orig >> 3);
  const int rowBase = (wg >> 4) * 256;   // M
  const int colBase = (wg & 15) * 256;   // N

  // Staging: thread covers slot-chunks c = tid and tid+512 (1024 x 16B/slot).
  // Global source pre-swizzled: row = c>>2, kchunk = (c&3) ^ ((row>>1)&3).
  const u16* gA[2];
  const u16* gB[2];
  int sOff[2];
#pragma unroll
  for (int j = 0; j < 2; ++j) {
    int c  = j * 512 + tid;
    int r  = c >> 2;
    int qg = (c & 3) ^ ((r >> 1) & 3);
    gA[j]   = Xb + (size_t)(rowBase + r) * KDIM + qg * 8;
    gB[j]   = Qb + (size_t)(colBase + r) * KDIM + qg * 8;
    sOff[j] = c * 8;  // u16 elements within a slot
  }

#define STAGE_A(s, kt)                                              \
  do {                                                              \
    load_lds16(gA[0] + (kt), (u16*)As + (s) * 8192 + sOff[0]);      \
    load_lds16(gA[1] + (kt), (u16*)As + (s) * 8192 + sOff[1]);      \
  } while (0)
#define STAGE_B(s, kt)                                              \
  do {                                                              \
    load_lds16(gB[0] + (kt), (u16*)Bs + (s) * 8192 + sOff[0]);      \
    load_lds16(gB[1] + (kt), (u16*)Bs + (s) * 8192 + sOff[1]);      \
  } while (0)

  // Fragment LDS element offsets (slot-relative), swizzle-matched.
  int ac[8], bc[4];
#pragma unroll
  for (int i = 0; i < 8; ++i) {
    int r = wm * 128 + i * 16 + l16;
    ac[i] = (r * 4 + (quad ^ ((r >> 1) & 3))) * 8;
  }
#pragma unroll
  for (int j = 0; j < 4; ++j) {
    int r = wn * 64 + j * 16 + l16;
    bc[j] = (r * 4 + (quad ^ ((r >> 1) & 3))) * 8;
  }

#define RD_A(d, i, s) d = *(const bf16x8*)((const u16*)As + (s) * 8192 + ac[i])
#define RD_B(d, j, s) d = *(const bf16x8*)((const u16*)Bs + (s) * 8192 + bc[j])

  f32x4 acc[8][4] = {};
  bf16x8 af[4], bf[4];

  // Prologue: stage tiles 0,1,2 into slots 0,1,2 (12 calls), drain tile 0.
  STAGE_A(0, 0);  STAGE_B(0, 0);
  STAGE_A(1, 32); STAGE_B(1, 32);
  STAGE_A(2, 64); STAGE_B(2, 64);
  VMCNT8();
  FENCE(); BARRIER(); FENCE();

  // Tile body: slot S is compile-time (4x unrolled ring).
#define TILE_BODY(S)                                                       \
  do {                                                                     \
    const int kt = (t + 3 < NTILE) ? (t + 3) * 32 : 0;                     \
    /* ---- phase 0: Mreps 0-3 ---- */                                     \
    RD_A(af[0], 0, S); RD_A(af[1], 1, S);                                  \
    RD_A(af[2], 2, S); RD_A(af[3], 3, S);                                  \
    RD_B(bf[0], 0, S); RD_B(bf[1], 1, S);                                  \
    RD_B(bf[2], 2, S); RD_B(bf[3], 3, S);                                  \
    STAGE_A(((S) + 3) & 3, kt);                                            \
    FENCE(); BARRIER(); FENCE();                                           \
    __builtin_amdgcn_s_setprio(1);                                         \
    MFMA_BLK(0);                                                           \
    __builtin_amdgcn_s_setprio(0);                                         \
    FENCE(); BARRIER(); FENCE();                                           \
    /* ---- phase 1: Mreps 4-7 ---- */                                     \
    RD_A(af[0], 4, S); RD_A(af[1], 5, S);                                  \
    RD_A(af[2], 6, S); RD_A(af[3], 7, S);                                  \
    STAGE_B(((S) + 3) & 3, kt);                                            \
    FENCE(); BARRIER(); FENCE();                                           \
    __builtin_amdgcn_s_setprio(1);                                         \
    MFMA_BLK(4);                                                           \
    __builtin_amdgcn_s_setprio(0);                                         \
    VMCNT8();                                                              \
    FENCE(); BARRIER(); FENCE();                                           \
  } while (0)

  int t = 0;
  for (int it = 0; it < NTILE / 4; ++it) {
    TILE_BODY(0); ++t;
    TILE_BODY(1); ++t;
    TILE_BODY(2); ++t;
    TILE_BODY(3); ++t;
  }

  // Epilogue: C/D layout col = lane&15, row = quad*4 + reg (verified)
  float bv[4];
#pragma unroll
  for (int j = 0; j < 4; ++j) bv[j] = bias[colBase + wn * 64 + j * 16 + l16];

#pragma unroll
  for (int i = 0; i < 8; ++i) {
#pragma unroll
    for (int r = 0; r < 4; ++r) {
      int grow = rowBase + wm * 128 + i * 16 + quad * 4 + r;
      float* crow = C + (size_t)grow * NDIM + colBase + wn * 64 + l16;
#pragma unroll
      for (int j = 0; j < 4; ++j) {
        crow[j * 16] = acc[i][j][r] + bv[j];
      }
    }
  }
}

// ---------------------------------------------------------------- launch ----

extern "C" void kernel_launch(void* const* d_in, const int* in_sizes, int n_in,
                              void* d_out, int out_size, void* d_ws, size_t ws_size,
                              hipStream_t stream) {
  const float* x    = (const float*)d_in[0];
  const float* w    = (const float*)d_in[1];
  const float* bias = (const float*)d_in[2];
  float* out = (float*)d_out;

  // workspace: Xb bf16 [MDIM*KDIM] then Qb bf16 [NDIM*KDIM]  (= 100.7 MB)
  u16* xb = (u16*)d_ws;
  u16* qb = xb + (size_t)MDIM * KDIM;

  cvt_kernel<<<(unsigned)(XBLOCKS + WBLOCKS), 256, 0, stream>>>(x, xb, w, qb);

  dim3 grid(NDIM / 256, MDIM / 256);   // (16, 32)
  gemm_tern_kernel<<<grid, 512, 0, stream>>>(xb, qb, bias, out);
}